// Round 18
// baseline (83.820 us; speedup 1.0000x reference)
//
#include <hip/hip_runtime.h>

typedef unsigned short u16;
typedef unsigned int u32;
typedef _Float16 f16x8 __attribute__((ext_vector_type(8)));
typedef float f32x16 __attribute__((ext_vector_type(16)));

#define B_ 8
#define C_ 64
#define H_ 112
#define W_ 112
#define HW_ 12544
#define F_ 128
#define OH_ 110
#define OW_ 110
#define OWOH 12100
#define NPOS 96800
#define KK_ 576
#define NT_ 384           // output positions per block
#define NWGQ 1012         // 253 n-blocks x 4 f-quarters <= 1024: one round at 4 blk/CU
#define OCTSTRIDE 802816  // B_*W_*H_*8 elems per c-oct plane
#define AELEMS 73728      // F_*KK_ fp16 elems (kT total)
#define AQUAR 18432       // 32f x 576k fp16 = 36KB LDS per block

__device__ __forceinline__ void gl_lds16(const void* g, void* l) {
  __builtin_amdgcn_global_load_lds((const __attribute__((address_space(1))) void*)g,
                                   (__attribute__((address_space(3))) void*)l,
                                   16, 0, 0);
}

// ---- fused prep: blocks 0..895 transpose input; blocks 896..931 convert kernel ----
// xT [c_oct][b][w][h]{8c} fp16 ; kT A'[ko16][khalf][128f][8c] fp16 (32x32x16 frag order)
__global__ __launch_bounds__(256) void prep_all(const float* __restrict__ in,
                                                const float* __restrict__ k,
                                                u16* __restrict__ xT,
                                                u16* __restrict__ kT) {
  const int bid = blockIdx.x;
  const int tid = threadIdx.x;
  if (bid >= 896) {
    const int base = (bid - 896) * 2048;
#pragma unroll
    for (int t = 0; t < 8; ++t) {
      int idx = base + t * 256 + tid;
      int c = idx & 7;
      int f = (idx >> 3) & 127;
      int hf = (idx >> 10) & 1;
      int ko16 = idx >> 11;
      _Float16 h = (_Float16)k[f * KK_ + ko16 * 16 + hf * 8 + c];
      kT[idx] = __builtin_bit_cast(u16, h);
    }
    return;
  }
  __shared__ float tile[8][8][113];
  const int b = bid / 112;
  const int r = bid % 112;
  const int oct = r / 14;
  const int hs = (r % 14) * 8;

  for (int idx = tid; idx < 8 * 8 * 112; idx += 256) {
    int c = idx / 896;
    int rem = idx - c * 896;
    int h = rem / 112;
    int w = rem - h * 112;
    tile[c][h][w] = in[(((size_t)(b * 64 + oct * 8 + c)) * 112 + (hs + h)) * 112 + w];
  }
  __syncthreads();

  for (int idx = tid; idx < 896; idx += 256) {
    int w = idx >> 3;
    int h = idx & 7;
    f16x8 v;
#pragma unroll
    for (int c = 0; c < 8; ++c) v[c] = (_Float16)tile[c][h][w];
    size_t o = ((((size_t)oct * B_ + b) * W_ + w) * H_ + (hs + h)) * 8;
    *(f16x8*)(xT + o) = v;
  }
}

// ---------- main: 32f x 384n per block, A-QUARTER in 36KB LDS, 4 blocks/CU = 4 waves/SIMD ----------
// Occupancy is the only lever that has ever moved conv (r9 1/SIMD: 40.9 -> r10 2/SIMD: 34.9).
// This pushes to 4/SIMD: A-tile quartered (36KB LDS), acc[3] = 48 VGPR, ~110 total under
// the 128 cap of __launch_bounds__(256,4). Grid 1012 <= 1024: one dispatch round.
// Barrier-free K-loop, B in-step (explicit prefetch was null r12 vs r13; saves regs).
// B L2 traffic doubles (~440MB) -- proven non-binding by the r13/r16/r17 traffic matrix.
__global__ __launch_bounds__(256, 4) void conv_mfma(
    const u16* __restrict__ xT, const u16* __restrict__ kT,
    float* __restrict__ out) {
  __shared__ u16 lds[AQUAR];  // 36KB; 4 blocks/CU

  const int tid = threadIdx.x;
  const int wave = tid >> 6;
  const int lane = tid & 63;
  const int l31 = lane & 31;
  const int hi = lane >> 5;

  const int wg = blockIdx.x;   // identity mapping (proven equal to swizzles)
  const int nblk = wg >> 2;
  const int fq = wg & 3;       // f-quarter: f = fq*32 .. fq*32+31
  const int n0 = nblk * NT_ + wave * 96;

  // ---- B addressing: per-lane position offsets, 3 x 32 = 96 n per wave
  int posOff[3];
#pragma unroll
  for (int ni = 0; ni < 3; ++ni) {
    int n = n0 + ni * 32 + l31;
    if (n >= NPOS) n = 0;
    int b = n / OWOH;
    int r = n - b * OWOH;
    int w = r / OH_;
    int h = r - w * OH_;
    posOff[ni] = ((b * W_ + w) * H_ + h) * 8;
  }

  // ---- stage this block's A-quarter: 2304 16B-chunks / 256 thr = 9 per thread.
  // LDS chunk m = q64*32 + f_local ; src chunk = q64*128 + fq*32 + f_local
#pragma unroll
  for (int it = 0; it < 9; ++it) {
    const int m = it * 256 + tid;
    const int src = ((m >> 5) << 7) + (fq << 5) + (m & 31);
    gl_lds16(kT + src * 8, (char*)lds + m * 16);
  }
  __syncthreads();  // the ONLY barrier

  f32x16 acc[3] = {};

#pragma unroll
  for (int s = 0; s < 18; ++s) {
    const int tap = s >> 1;
    const int half = s & 1;
    const int i = tap / 3;      // W offset
    const int j = tap - i * 3;  // H offset
    const int sShift = (i * H_ + j) * 8;

    // B: 6 per-lane 16B loads from L2 (barrier-free loop -> freely schedulable)
    f16x8 bh[6];
#pragma unroll
    for (int ni = 0; ni < 3; ++ni)
#pragma unroll
      for (int t = 0; t < 2; ++t)
        bh[ni * 2 + t] = *(const f16x8*)(xT + (half * 4 + t * 2 + hi) * OCTSTRIDE +
                                         posOff[ni] + sShift);

    // A: 2 ds_read_b128; elem = ((q64*2+hi)*32 + l31)*8, q64 = s*2+t
    f16x8 ah[2];
#pragma unroll
    for (int t = 0; t < 2; ++t)
      ah[t] = *(const f16x8*)&lds[((((s * 2 + t) * 2 + hi) << 5) + l31) * 8];

#pragma unroll
    for (int t = 0; t < 2; ++t)
#pragma unroll
      for (int ni = 0; ni < 3; ++ni)
        acc[ni] = __builtin_amdgcn_mfma_f32_32x32x16_f16(ah[t], bh[ni * 2 + t], acc[ni], 0, 0, 0);
  }

  // epilogue: col = lane&31 -> n; row = (reg&3)+8*(reg>>2)+4*hi within fq*32
#pragma unroll
  for (int ni = 0; ni < 3; ++ni) {
    int n = n0 + ni * 32 + l31;
    if (n >= NPOS) continue;
    int b = n / OWOH;
    int r = n - b * OWOH;
    int w = r / OH_;
    int h = r - w * OH_;
    float* op = out + ((size_t)(b * F_) * OW_ + w) * OH_ + h;
    const int fbase = fq * 32 + 4 * hi;
#pragma unroll
    for (int reg = 0; reg < 16; ++reg) {
      int f = fbase + (reg & 3) + 8 * (reg >> 2);
      op[(size_t)f * OWOH] = acc[ni][reg];
    }
  }
}

// ---------------- correctness fallback (ws too small) ----------------
__global__ void naive_conv(const float* __restrict__ in, const float* __restrict__ ker,
                           float* __restrict__ out) {
  int idx = blockIdx.x * 256 + threadIdx.x;
  const int total = B_ * F_ * OW_ * OH_;
  if (idx >= total) return;
  int h = idx % OH_;
  int w = (idx / OH_) % OW_;
  int f = (idx / (OW_ * OH_)) % F_;
  int b = idx / (F_ * OW_ * OH_);
  float s = 0.f;
  for (int tap = 0; tap < 9; ++tap) {
    int i = tap / 3, j = tap % 3;
    const float* ip = in + ((size_t)b * C_ * H_ + (h + j)) * W_ + (w + i);
    const float* kp = ker + (size_t)f * KK_ + tap * C_;
    for (int c = 0; c < C_; ++c) s += ip[(size_t)c * HW_] * kp[c];
  }
  out[idx] = s;
}

extern "C" void kernel_launch(void* const* d_in, const int* in_sizes, int n_in,
                              void* d_out, int out_size, void* d_ws, size_t ws_size,
                              hipStream_t stream) {
  const float* in = (const float*)d_in[0];
  const float* ker = (const float*)d_in[1];
  float* out = (float*)d_out;

  const size_t xElems = (size_t)B_ * H_ * W_ * C_;  // 6,422,528
  const size_t need = (xElems + AELEMS) * 2;        // ~13 MB fp16

  if (ws_size < need) {
    int total = B_ * F_ * OW_ * OH_;
    naive_conv<<<(total + 255) / 256, 256, 0, stream>>>(in, ker, out);
    return;
  }

  u16* xT = (u16*)d_ws;
  u16* kT = xT + xElems;

  prep_all<<<932, 256, 0, stream>>>(in, ker, xT, kT);
  conv_mfma<<<NWGQ, 256, 0, stream>>>(xT, kT, out);
}

// Round 19
// 42.373 us; speedup vs baseline: 1.9781x; 1.9781x over previous
//
#include <hip/hip_runtime.h>

typedef unsigned short u16;
typedef unsigned int u32;
typedef _Float16 f16x8 __attribute__((ext_vector_type(8)));
typedef float f32x16 __attribute__((ext_vector_type(16)));

#define B_ 8
#define C_ 64
#define H_ 112
#define W_ 112
#define HW_ 12544
#define F_ 128
#define OH_ 110
#define OW_ 110
#define OWOH 12100
#define NPOS 96800
#define KK_ 576
#define NT_ 384           // output positions per n-block
#define NWGQ 1012         // 253 n-blocks x 4 f-quarters; 4 blk/CU (36KB LDS, 52 VGPR)
#define OCTSTRIDE 802816  // B_*W_*H_*8 elems per c-oct plane
#define AELEMS 73728      // F_*KK_ fp16 elems (kT total)
#define AQUAR 18432       // 32f x 576k fp16 = 36KB LDS per block

__device__ __forceinline__ void gl_lds16(const void* g, void* l) {
  __builtin_amdgcn_global_load_lds((const __attribute__((address_space(1))) void*)g,
                                   (__attribute__((address_space(3))) void*)l,
                                   16, 0, 0);
}

// ---- fused prep: blocks 0..895 transpose input; blocks 896..931 convert kernel ----
// xT [c_oct][b][w][h]{8c} fp16 ; kT A'[ko16][khalf][128f][8c] fp16 (32x32x16 frag order)
__global__ __launch_bounds__(256) void prep_all(const float* __restrict__ in,
                                                const float* __restrict__ k,
                                                u16* __restrict__ xT,
                                                u16* __restrict__ kT) {
  const int bid = blockIdx.x;
  const int tid = threadIdx.x;
  if (bid >= 896) {
    const int base = (bid - 896) * 2048;
#pragma unroll
    for (int t = 0; t < 8; ++t) {
      int idx = base + t * 256 + tid;
      int c = idx & 7;
      int f = (idx >> 3) & 127;
      int hf = (idx >> 10) & 1;
      int ko16 = idx >> 11;
      _Float16 h = (_Float16)k[f * KK_ + ko16 * 16 + hf * 8 + c];
      kT[idx] = __builtin_bit_cast(u16, h);
    }
    return;
  }
  __shared__ float tile[8][8][113];
  const int b = bid / 112;
  const int r = bid % 112;
  const int oct = r / 14;
  const int hs = (r % 14) * 8;

  for (int idx = tid; idx < 8 * 8 * 112; idx += 256) {
    int c = idx / 896;
    int rem = idx - c * 896;
    int h = rem / 112;
    int w = rem - h * 112;
    tile[c][h][w] = in[(((size_t)(b * 64 + oct * 8 + c)) * 112 + (hs + h)) * 112 + w];
  }
  __syncthreads();

  for (int idx = tid; idx < 896; idx += 256) {
    int w = idx >> 3;
    int h = idx & 7;
    f16x8 v;
#pragma unroll
    for (int c = 0; c < 8; ++c) v[c] = (_Float16)tile[c][h][w];
    size_t o = ((((size_t)oct * B_ + b) * W_ + w) * H_ + (hs + h)) * 8;
    *(f16x8*)(xT + o) = v;
  }
}

// ---------- main: r18 config + bijective XCD swizzle grouping f-quartets ----------
// r18 clean counters: FETCH 205MB (>= 8 XCDs x whole 12.8MB input, round-robin wg%8->XCD
// scatters consecutive nblks across XCDs) -> fetch-bound, conv 72us. Fix: m204-form
// bijective swizzle (nwg=1012: q=126, r=4) so each XCD owns ~32 CONSECUTIVE nblks incl.
// all 4 f-quarters -> per-XCD B footprint ~1.6MB < 4MB L2. Everything else = r18
// (36KB LDS, 52 VGPR, 4 blk/CU, occupancy 36.7% proven).
__global__ __launch_bounds__(256, 4) void conv_mfma(
    const u16* __restrict__ xT, const u16* __restrict__ kT,
    float* __restrict__ out) {
  __shared__ u16 lds[AQUAR];  // 36KB; 4 blocks/CU

  const int tid = threadIdx.x;
  const int wave = tid >> 6;
  const int lane = tid & 63;
  const int l31 = lane & 31;
  const int hi = lane >> 5;

  // bijective XCD swizzle (HW round-robin orig&7 -> XCD; chunk per XCD):
  // nwg=1012: q=126, r=4 -> xcd<4 get 127 work items, else 126.
  const int orig = blockIdx.x;
  const int xcd = orig & 7;
  const int sub = orig >> 3;
  const int work = (xcd < 4 ? xcd * 127 : 508 + (xcd - 4) * 126) + sub;
  const int nblk = work >> 2;
  const int fq = work & 3;  // f-quarter: f = fq*32 .. fq*32+31
  const int n0 = nblk * NT_ + wave * 96;

  // ---- B addressing: per-lane position offsets, 3 x 32 = 96 n per wave
  int posOff[3];
#pragma unroll
  for (int ni = 0; ni < 3; ++ni) {
    int n = n0 + ni * 32 + l31;
    if (n >= NPOS) n = 0;
    int b = n / OWOH;
    int r = n - b * OWOH;
    int w = r / OH_;
    int h = r - w * OH_;
    posOff[ni] = ((b * W_ + w) * H_ + h) * 8;
  }

  // ---- stage this block's A-quarter: 2304 16B-chunks / 256 thr = 9 per thread.
  // LDS chunk m = q64*32 + f_local ; src chunk = q64*128 + fq*32 + f_local
#pragma unroll
  for (int it = 0; it < 9; ++it) {
    const int m = it * 256 + tid;
    const int src = ((m >> 5) << 7) + (fq << 5) + (m & 31);
    gl_lds16(kT + src * 8, (char*)lds + m * 16);
  }
  __syncthreads();  // the ONLY barrier

  f32x16 acc[3] = {};

#pragma unroll
  for (int s = 0; s < 18; ++s) {
    const int tap = s >> 1;
    const int half = s & 1;
    const int i = tap / 3;      // W offset
    const int j = tap - i * 3;  // H offset
    const int sShift = (i * H_ + j) * 8;

    // B: 6 per-lane 16B loads from L2 (barrier-free loop -> freely schedulable)
    f16x8 bh[6];
#pragma unroll
    for (int ni = 0; ni < 3; ++ni)
#pragma unroll
      for (int t = 0; t < 2; ++t)
        bh[ni * 2 + t] = *(const f16x8*)(xT + (half * 4 + t * 2 + hi) * OCTSTRIDE +
                                         posOff[ni] + sShift);

    // A: 2 ds_read_b128; elem = ((q64*2+hi)*32 + l31)*8, q64 = s*2+t
    f16x8 ah[2];
#pragma unroll
    for (int t = 0; t < 2; ++t)
      ah[t] = *(const f16x8*)&lds[((((s * 2 + t) * 2 + hi) << 5) + l31) * 8];

#pragma unroll
    for (int t = 0; t < 2; ++t)
#pragma unroll
      for (int ni = 0; ni < 3; ++ni)
        acc[ni] = __builtin_amdgcn_mfma_f32_32x32x16_f16(ah[t], bh[ni * 2 + t], acc[ni], 0, 0, 0);
  }

  // epilogue: col = lane&31 -> n; row = (reg&3)+8*(reg>>2)+4*hi within fq*32
#pragma unroll
  for (int ni = 0; ni < 3; ++ni) {
    int n = n0 + ni * 32 + l31;
    if (n >= NPOS) continue;
    int b = n / OWOH;
    int r = n - b * OWOH;
    int w = r / OH_;
    int h = r - w * OH_;
    float* op = out + ((size_t)(b * F_) * OW_ + w) * OH_ + h;
    const int fbase = fq * 32 + 4 * hi;
#pragma unroll
    for (int reg = 0; reg < 16; ++reg) {
      int f = fbase + (reg & 3) + 8 * (reg >> 2);
      op[(size_t)f * OWOH] = acc[ni][reg];
    }
  }
}

// ---------------- correctness fallback (ws too small) ----------------
__global__ void naive_conv(const float* __restrict__ in, const float* __restrict__ ker,
                           float* __restrict__ out) {
  int idx = blockIdx.x * 256 + threadIdx.x;
  const int total = B_ * F_ * OW_ * OH_;
  if (idx >= total) return;
  int h = idx % OH_;
  int w = (idx / OH_) % OW_;
  int f = (idx / (OW_ * OH_)) % F_;
  int b = idx / (F_ * OW_ * OH_);
  float s = 0.f;
  for (int tap = 0; tap < 9; ++tap) {
    int i = tap / 3, j = tap % 3;
    const float* ip = in + ((size_t)b * C_ * H_ + (h + j)) * W_ + (w + i);
    const float* kp = ker + (size_t)f * KK_ + tap * C_;
    for (int c = 0; c < C_; ++c) s += ip[(size_t)c * HW_] * kp[c];
  }
  out[idx] = s;
}

extern "C" void kernel_launch(void* const* d_in, const int* in_sizes, int n_in,
                              void* d_out, int out_size, void* d_ws, size_t ws_size,
                              hipStream_t stream) {
  const float* in = (const float*)d_in[0];
  const float* ker = (const float*)d_in[1];
  float* out = (float*)d_out;

  const size_t xElems = (size_t)B_ * H_ * W_ * C_;  // 6,422,528
  const size_t need = (xElems + AELEMS) * 2;        // ~13 MB fp16

  if (ws_size < need) {
    int total = B_ * F_ * OW_ * OH_;
    naive_conv<<<(total + 255) / 256, 256, 0, stream>>>(in, ker, out);
    return;
  }

  u16* xT = (u16*)d_ws;
  u16* kT = xT + xElems;

  prep_all<<<932, 256, 0, stream>>>(in, ker, xT, kT);
  conv_mfma<<<NWGQ, 256, 0, stream>>>(xT, kT, out);
}

// Round 20
// 40.408 us; speedup vs baseline: 2.0744x; 1.0486x over previous
//
#include <hip/hip_runtime.h>

typedef unsigned short u16;
typedef unsigned int u32;
typedef _Float16 f16x8 __attribute__((ext_vector_type(8)));
typedef float f32x16 __attribute__((ext_vector_type(16)));

#define B_ 8
#define C_ 64
#define H_ 112
#define W_ 112
#define HW_ 12544
#define F_ 128
#define OH_ 110
#define OW_ 110
#define OWOH 12100
#define NPOS 96800
#define KK_ 576
#define NT_ 384           // output positions per block
#define NWGF 506          // 253 n-blocks x 2 f-halves
#define OCTSTRIDE 802816  // B_*W_*H_*8 elems per c-oct plane
#define AELEMS 73728      // F_*KK_ fp16 elems (kT total)
#define AKHALF 18432      // 64f x 288k fp16 = 36KB LDS (one K-half of the A-half)

__device__ __forceinline__ void gl_lds16(const void* g, void* l) {
  __builtin_amdgcn_global_load_lds((const __attribute__((address_space(1))) void*)g,
                                   (__attribute__((address_space(3))) void*)l,
                                   16, 0, 0);
}

// ---- fused prep: blocks 0..895 transpose input; blocks 896..931 convert kernel ----
// xT [c_oct][b][w][h]{8c} fp16 ; kT A'[ko16][khalf][128f][8c] fp16 (32x32x16 frag order)
__global__ __launch_bounds__(256) void prep_all(const float* __restrict__ in,
                                                const float* __restrict__ k,
                                                u16* __restrict__ xT,
                                                u16* __restrict__ kT) {
  const int bid = blockIdx.x;
  const int tid = threadIdx.x;
  if (bid >= 896) {
    const int base = (bid - 896) * 2048;
#pragma unroll
    for (int t = 0; t < 8; ++t) {
      int idx = base + t * 256 + tid;
      int c = idx & 7;
      int f = (idx >> 3) & 127;
      int hf = (idx >> 10) & 1;
      int ko16 = idx >> 11;
      _Float16 h = (_Float16)k[f * KK_ + ko16 * 16 + hf * 8 + c];
      kT[idx] = __builtin_bit_cast(u16, h);
    }
    return;
  }
  __shared__ float tile[8][8][113];
  const int b = bid / 112;
  const int r = bid % 112;
  const int oct = r / 14;
  const int hs = (r % 14) * 8;

  for (int idx = tid; idx < 8 * 8 * 112; idx += 256) {
    int c = idx / 896;
    int rem = idx - c * 896;
    int h = rem / 112;
    int w = rem - h * 112;
    tile[c][h][w] = in[(((size_t)(b * 64 + oct * 8 + c)) * 112 + (hs + h)) * 112 + w];
  }
  __syncthreads();

  for (int idx = tid; idx < 896; idx += 256) {
    int w = idx >> 3;
    int h = idx & 7;
    f16x8 v;
#pragma unroll
    for (int c = 0; c < 8; ++c) v[c] = (_Float16)tile[c][h][w];
    size_t o = ((((size_t)oct * B_ + b) * W_ + w) * H_ + (hs + h)) * 8;
    *(f16x8*)(xT + o) = v;
  }
}

// ------- main: r10's 64f x 384n tile at 3 blocks/CU via sequential K-half A-staging -------
// r10 (best, 37.3us) is capped at 2 blk/CU by 72KB LDS. Stage A's K in two 36KB halves
// (same buffer, re-staged mid-kernel): LDS 36KB -> 3 blk/CU = 3 waves/SIMD (+50% TLP,
// the only lever that has ever moved conv: r9 1/SIMD 40.9 -> r10 2/SIMD 34.9).
// Cost: 2 extra barriers, zero extra bytes. VGPR target 170 at (256,3); live set ~155.
// Everything else (tiles, B-path, swizzle, epilogue) verbatim r10.
__global__ __launch_bounds__(256, 3) void conv_mfma(
    const u16* __restrict__ xT, const u16* __restrict__ kT,
    float* __restrict__ out) {
  __shared__ u16 lds[AKHALF];  // 36KB; 3 blocks/CU

  const int tid = threadIdx.x;
  const int wave = tid >> 6;
  const int lane = tid & 63;
  const int l31 = lane & 31;
  const int hi = lane >> 5;

  // bijective XCD swizzle for 506 (q=63, r=2): f-half pairs + consecutive nblks per XCD
  // (round-robin orig&7 -> XCD confirmed by r18->r19 FETCH recovery).
  const int orig = blockIdx.x;
  const int xcd = orig & 7;
  const int sub = orig >> 3;
  const int wg = (xcd < 2 ? xcd * 64 : 128 + (xcd - 2) * 63) + sub;
  const int nblk = wg >> 1;
  const int fh = wg & 1;  // which 64-filter half
  const int n0 = nblk * NT_ + wave * 96;

  // ---- B addressing: per-lane position offsets, 3 x 32 = 96 n per wave
  int posOff[3];
#pragma unroll
  for (int ni = 0; ni < 3; ++ni) {
    int n = n0 + ni * 32 + l31;
    if (n >= NPOS) n = 0;
    int b = n / OWOH;
    int r = n - b * OWOH;
    int w = r / OH_;
    int h = r - w * OH_;
    posOff[ni] = ((b * W_ + w) * H_ + h) * 8;
  }

  // ---- stage one K-half of this block's A-half: 2304 chunks / 256 thr = 9 each.
  // LDS chunk m = (g_l*2+hi)*64 + f_local (g_l in [0,18)); src chunk =
  // ((m>>6) + half*36)*128 + fh*64 + (m&63)   [kT chunk = (g*2+hi)*128 + f]
  auto stageA = [&](int half) {
#pragma unroll
    for (int it = 0; it < 9; ++it) {
      const int m = it * 256 + tid;
      const int src = (((m >> 6) + half * 36) << 7) + (fh << 6) + (m & 63);
      gl_lds16(kT + src * 8, (char*)lds + m * 16);
    }
  };

  f32x16 acc[2][3] = {};

#define STEP(S, HALFBUF)                                                                 \
  {                                                                                      \
    const int tap = (S) >> 1;                                                            \
    const int bhalf = (S)&1;                                                             \
    const int i_ = tap / 3, j_ = tap - i_ * 3;                                           \
    const int sShift = (i_ * H_ + j_) * 8;                                               \
    f16x8 bh[6];                                                                         \
    _Pragma("unroll") for (int ni = 0; ni < 3; ++ni)                                     \
        _Pragma("unroll") for (int t = 0; t < 2; ++t)                                    \
            bh[ni * 2 + t] = *(const f16x8*)(xT + (bhalf * 4 + t * 2 + hi) * OCTSTRIDE + \
                                             posOff[ni] + sShift);                       \
    f16x8 ah[4];                                                                         \
    const int sl = (S)-9 * (HALFBUF);                                                    \
    _Pragma("unroll") for (int t = 0; t < 2; ++t)                                        \
        _Pragma("unroll") for (int mi = 0; mi < 2; ++mi)                                 \
            ah[t * 2 + mi] =                                                             \
                *(const f16x8*)&lds[((((sl * 2 + t) * 2 + hi) << 6) + mi * 32 + l31) * 8]; \
    _Pragma("unroll") for (int t = 0; t < 2; ++t)                                        \
        _Pragma("unroll") for (int mi = 0; mi < 2; ++mi)                                 \
            _Pragma("unroll") for (int ni = 0; ni < 3; ++ni)                             \
                acc[mi][ni] = __builtin_amdgcn_mfma_f32_32x32x16_f16(                    \
                    ah[t * 2 + mi], bh[ni * 2 + t], acc[mi][ni], 0, 0, 0);               \
  }

  stageA(0);
  __syncthreads();  // K-half 0 visible
  STEP(0, 0) STEP(1, 0) STEP(2, 0) STEP(3, 0) STEP(4, 0)
  STEP(5, 0) STEP(6, 0) STEP(7, 0) STEP(8, 0)
  __syncthreads();  // all reads of buf done (WAR)
  stageA(1);
  __syncthreads();  // K-half 1 visible (vmcnt drained by barrier)
  STEP(9, 1) STEP(10, 1) STEP(11, 1) STEP(12, 1) STEP(13, 1)
  STEP(14, 1) STEP(15, 1) STEP(16, 1) STEP(17, 1)
#undef STEP

  // epilogue: col = lane&31 -> n; row = (reg&3)+8*(reg>>2)+4*hi within (fh*64 + mi*32)
#pragma unroll
  for (int ni = 0; ni < 3; ++ni) {
    int n = n0 + ni * 32 + l31;
    if (n >= NPOS) continue;
    int b = n / OWOH;
    int r = n - b * OWOH;
    int w = r / OH_;
    int h = r - w * OH_;
    float* op = out + ((size_t)(b * F_) * OW_ + w) * OH_ + h;
#pragma unroll
    for (int mi = 0; mi < 2; ++mi) {
      const int fbase = fh * 64 + mi * 32 + 4 * hi;
#pragma unroll
      for (int reg = 0; reg < 16; ++reg) {
        int f = fbase + (reg & 3) + 8 * (reg >> 2);
        op[(size_t)f * OWOH] = acc[mi][ni][reg];
      }
    }
  }
}

// ---------------- correctness fallback (ws too small) ----------------
__global__ void naive_conv(const float* __restrict__ in, const float* __restrict__ ker,
                           float* __restrict__ out) {
  int idx = blockIdx.x * 256 + threadIdx.x;
  const int total = B_ * F_ * OW_ * OH_;
  if (idx >= total) return;
  int h = idx % OH_;
  int w = (idx / OH_) % OW_;
  int f = (idx / (OW_ * OH_)) % F_;
  int b = idx / (F_ * OW_ * OH_);
  float s = 0.f;
  for (int tap = 0; tap < 9; ++tap) {
    int i = tap / 3, j = tap % 3;
    const float* ip = in + ((size_t)b * C_ * H_ + (h + j)) * W_ + (w + i);
    const float* kp = ker + (size_t)f * KK_ + tap * C_;
    for (int c = 0; c < C_; ++c) s += ip[(size_t)c * HW_] * kp[c];
  }
  out[idx] = s;
}

extern "C" void kernel_launch(void* const* d_in, const int* in_sizes, int n_in,
                              void* d_out, int out_size, void* d_ws, size_t ws_size,
                              hipStream_t stream) {
  const float* in = (const float*)d_in[0];
  const float* ker = (const float*)d_in[1];
  float* out = (float*)d_out;

  const size_t xElems = (size_t)B_ * H_ * W_ * C_;  // 6,422,528
  const size_t need = (xElems + AELEMS) * 2;        // ~13 MB fp16

  if (ws_size < need) {
    int total = B_ * F_ * OW_ * OH_;
    naive_conv<<<(total + 255) / 256, 256, 0, stream>>>(in, ker, out);
    return;
  }

  u16* xT = (u16*)d_ws;
  u16* kT = xT + xElems;

  prep_all<<<932, 256, 0, stream>>>(in, ker, xT, kT);
  conv_mfma<<<NWGF, 256, 0, stream>>>(xT, kT, out);
}